// Round 7
// baseline (45.417 us; speedup 1.0000x reference)
//
#include <hip/hip_runtime.h>

// Problem dims (fixed by harness setup_inputs)
#define NB 4
#define WR 320
#define NH 240
#define WL 320
#define NK 9
#define TW 16
#define NTILES 20
#define NS 10                     // h-pair steps per block (20 h / block)
#define HP 12                     // h-chunks
#define SLOTS 152                 // band rows [w0-96, w0+55], exact (R5-verified)
#define NI 19                     // band staging instrs per step (8 slots each)
#define BANDF (SLOTS * 2 * TW)    // 4864 floats: [slot][hh2][c16]
#define BUFSZ (BANDF + 64)        // + 64 disp floats
#define RSTRIDE ((size_t)NH * WL) // 76800 floats
#define NBLK (NB * NTILES * HP)   // 960 = fully resident at 4 blocks/CU
#define NXCD 8

typedef const __attribute__((address_space(1))) void* gas_t;
typedef __attribute__((address_space(3))) void* las_t;

__device__ __forceinline__ void gld16(const float* g, float* l) {
  __builtin_amdgcn_global_load_lds((gas_t)g, (las_t)l, 16, 0, 0);
}
__device__ __forceinline__ void gld4(const float* g, float* l) {
  __builtin_amdgcn_global_load_lds((gas_t)g, (las_t)l, 4, 0, 0);
}

// band LDS addr: slot*32 + hh*16 + c; bank = (hh*16+c)%32 -> 2-way = free
template <int L>
__device__ __forceinline__ float pooledf(const float* p, int j, int sbase,
                                         int hc) {
  const int a = ((j << L) + sbase) * 32 + hc;
  float v = p[a];
#pragma unroll
  for (int t = 1; t < (1 << L); ++t) v += p[a + t * 32];
  return v;
}

// One wave = one pyramid level, running a 10-step double-buffered pipeline:
// per step, all vmem per wave is uniform (5 gld_lds stage + 5 stores), so
// counted s_waitcnt immediates are exact: vmcnt(5) first/last, vmcnt(10)
// steady (= 5 stores(q-1) + 5 stage(q+1) newer than batch q).
template <int L>
__device__ __forceinline__ void run_level(const float* __restrict__ corr,
                                          const float* __restrict__ disp,
                                          float* __restrict__ out, float* lds,
                                          int b, int h0, int w0, int lane) {
  const int dsr = lane >> 3;       // staging: slot within 8-slot group
  const int sh = (lane >> 2) & 1;  // staging: h within pair
  const int c4 = (lane & 3) << 2;  // staging: float col
  const int kq2 = lane >> 5;       // compute: k parity
  const int hh = (lane >> 4) & 1;  // compute: h within pair
  const int c = lane & 15;         // compute: column
  const int hc = hh * 16 + c;
  const int sbase = 96 - w0;
  const float sc = 1.0f / (float)(1 << L);
  const int Wm1 = (WR >> L) - 1;
  const size_t cb = (size_t)b * WR * RSTRIDE;

  auto stage = [&](int qs) {
    float* bb = lds + (qs & 1) * BUFSZ;
#pragma unroll
    for (int i = L; i < NI; i += 4) {  // waves 0-2: 5 instrs; wave 3: 4
      int rr = w0 - 96 + 8 * i + dsr;
      rr = min(max(rr, 0), WR - 1);  // clamped slots never sampled; L2 dedups
      const float* src =
          corr + cb + ((size_t)rr * NH + (h0 + 2 * qs + sh)) * WL + w0 + c4;
      gld16(src, bb + i * 256);
    }
    if (L == 3) {  // wave 3's 5th instr: stage disp pair (lane slot = lane)
      const float* dsrc =
          disp + ((size_t)b * NH + (h0 + 2 * qs + ((lane >> 4) & 1))) * WL +
          w0 + (lane & 15);
      gld4(dsrc, bb + BANDF);
    }
  };

  stage(0);
  stage(1);

#pragma unroll
  for (int q = 0; q < NS; ++q) {
    if (q == 0 || q == NS - 1)
      asm volatile("s_waitcnt vmcnt(5)" ::: "memory");
    else
      asm volatile("s_waitcnt vmcnt(10)" ::: "memory");
    __builtin_amdgcn_s_barrier();
    __builtin_amdgcn_sched_barrier(0);

    const float* bp = lds + (q & 1) * BUFSZ;
    const float dsp = bp[BANDF + hc];
    const float fidx = ((float)(w0 + c) - dsp) * sc;
    const int hq = h0 + 2 * q + hh;

#pragma unroll
    for (int m = 0; m < 5; ++m) {
      const int kraw = kq2 + 2 * m;     // lane's k subset: evens / odds
      const int k = min(kraw, 8);       // keep invalid lane's reads in-band
      const float idx =
          fminf(fmaxf(fidx + (float)(k - 4), 0.0f), (float)Wm1);
      const int i0 = (int)idx;
      const int i1 = min(i0 + 1, Wm1);
      const float w = idx - (float)i0;
      const float v0 = pooledf<L>(bp, i0, sbase, hc);
      const float v1 = pooledf<L>(bp, i1, sbase, hc);
      if (kraw < NK) {
        out[((size_t)(b * (4 * NK) + L * NK + k) * NH + hq) * WL + w0 + c] =
            sc * fmaf(w, v1 - v0, v0);
      }
    }

    asm volatile("" ::: "memory");
    __builtin_amdgcn_s_barrier();  // all waves done reading buf[q&1]
    asm volatile("" ::: "memory");
    if (q + 2 < NS) stage(q + 2);  // prefetch 2 ahead into freed buffer
    asm volatile("" ::: "memory");
  }
}

extern "C" __global__ __launch_bounds__(256, 4) void corr_sample_kernel(
    const float* __restrict__ corr, const float* __restrict__ disp,
    float* __restrict__ out) {
  __shared__ float lds0[2 * BUFSZ];  // 38.5 KB -> 4 blocks/CU

  // bijective XCD chunking (960 = 8 x 120), tile-fastest so adjacent tiles
  // (sharing 128B-line halves) are co-resident on the same XCD L2
  const int bid = ((int)blockIdx.x & (NXCD - 1)) * (NBLK / NXCD) +
                  ((int)blockIdx.x >> 3);
  const int tile = bid % NTILES;
  const int rest = bid / NTILES;
  const int hp = rest % HP;
  const int b = rest / HP;
  const int w0 = tile * TW;
  const int h0 = hp * (2 * NS);

  const int lane = (int)threadIdx.x & 63;
  const int wv = (int)threadIdx.x >> 6;

  switch (wv) {
    case 0: run_level<0>(corr, disp, out, lds0, b, h0, w0, lane); break;
    case 1: run_level<1>(corr, disp, out, lds0, b, h0, w0, lane); break;
    case 2: run_level<2>(corr, disp, out, lds0, b, h0, w0, lane); break;
    default: run_level<3>(corr, disp, out, lds0, b, h0, w0, lane); break;
  }
}

extern "C" void kernel_launch(void* const* d_in, const int* in_sizes, int n_in,
                              void* d_out, int out_size, void* d_ws,
                              size_t ws_size, hipStream_t stream) {
  const float* corr = (const float*)d_in[0];
  const float* disp = (const float*)d_in[1];
  float* out = (float*)d_out;
  corr_sample_kernel<<<NBLK, 256, 0, stream>>>(corr, disp, out);
}

// Round 8
// 41.764 us; speedup vs baseline: 1.0875x; 1.0875x over previous
//
#include <hip/hip_runtime.h>

// Problem dims (fixed by harness setup_inputs)
#define NB 4
#define WR 320
#define NH 240
#define WL 320
#define NK 9
#define TW 16
#define NTILES 20
#define HH 2                       // h-rows per block (halved vs R5 -> 8 blocks/CU)
#define SLOTS 152                  // band rows [w0-96, w0+55], exact
#define NI 19                      // staging instrs: 8 slots x 2 h x 64 B each
#define DISPOFF (SLOTS * HH * TW)  // 4864 floats
#define LDSF (DISPOFF + 64)        // + disp (64 floats, half dup)
#define RSTRIDE ((size_t)NH * WL)  // 76800 floats
#define NBLK (NB * NTILES * (NH / HH))  // 9600
#define NXCD 8

typedef const __attribute__((address_space(1))) void* gas_t;
typedef __attribute__((address_space(3))) void* las_t;

__device__ __forceinline__ void gld16(const float* g, float* l) {
  __builtin_amdgcn_global_load_lds((gas_t)g, (las_t)l, 16, 0, 0);
}
__device__ __forceinline__ void gld4(const float* g, float* l) {
  __builtin_amdgcn_global_load_lds((gas_t)g, (las_t)l, 4, 0, 0);
}

// band LDS addr: slot*32 + hh*16 + c; bank = (hh*16+c)%32, slot-independent
// -> kpar pairs alias 2-way = free (m136)
template <int L>
__device__ __forceinline__ float pooledf(const float* p, int j, int sbase,
                                         int hc) {
  const int a = ((j << L) + sbase) * 32 + hc;
  float v = p[a];
#pragma unroll
  for (int t = 1; t < (1 << L); ++t) v += p[a + t * 32];
  return v;
}

template <int L>
__device__ __forceinline__ void sample_level(const float* __restrict__ lds,
                                             int lane, int b, int h0, int w0,
                                             float* __restrict__ out) {
  const int kpar = lane >> 5;      // k parity (evens / odds)
  const int hh = (lane >> 4) & 1;  // h within pair
  const int c = lane & 15;         // column
  const int hc = hh * 16 + c;
  const int sbase = 96 - w0;
  const float sc = 1.0f / (float)(1 << L);
  const int Wm1 = (WR >> L) - 1;

  const float dsp = lds[DISPOFF + hc];
  const float fidx = ((float)(w0 + c) - dsp) * sc;

#pragma unroll
  for (int m = 0; m < 5; ++m) {
    const int kraw = kpar + 2 * m;
    const int k = min(kraw, 8);  // keep invalid lanes' reads in-band
    const float idx = fminf(fmaxf(fidx + (float)(k - 4), 0.0f), (float)Wm1);
    const int i0 = (int)idx;
    const int i1 = min(i0 + 1, Wm1);
    const float w = idx - (float)i0;
    const float v0 = pooledf<L>(lds, i0, sbase, hc);
    const float v1 = pooledf<L>(lds, i1, sbase, hc);
    if (kraw < NK) {
      out[((size_t)(b * (4 * NK) + L * NK + k) * NH + (h0 + hh)) * WL + w0 +
          c] = sc * fmaf(w, v1 - v0, v0);
    }
  }
}

extern "C" __global__ __launch_bounds__(256, 8) void corr_sample_kernel(
    const float* __restrict__ corr, const float* __restrict__ disp,
    float* __restrict__ out) {
  __shared__ float lds0[LDSF];  // 19.3 KB -> 8 blocks/CU = 32 waves (max)

  // bijective XCD chunking (9600 = 8 x 1200), tile-fastest
  const int bid = ((int)blockIdx.x & (NXCD - 1)) * (NBLK / NXCD) +
                  ((int)blockIdx.x >> 3);
  const int tile = bid % NTILES;
  const int rest = bid / NTILES;
  const int hp = rest % (NH / HH);
  const int b = rest / (NH / HH);
  const int w0 = tile * TW;
  const int h0 = hp * HH;

  const int tid = (int)threadIdx.x;
  const int lane = tid & 63;
  const int wv = tid >> 6;  // wave id == pyramid level

  // ---- stage band: 19 instrs, each = 8 slots x 2 h x 64 B ----
  {
    const int ds = lane >> 3;        // slot within 8-group
    const int sh = (lane >> 2) & 1;  // h within pair
    const int c4 = (lane & 3) << 2;  // float col
    const size_t cb = (size_t)b * WR * RSTRIDE;
    for (int g = wv; g < NI; g += 4) {  // waves 0-2: 5 instrs; wave 3: 4
      int rr = w0 - 96 + 8 * g + ds;
      rr = min(max(rr, 0), WR - 1);  // clamped slots never sampled; L2 dedups
      const float* src =
          corr + cb + ((size_t)rr * NH + (h0 + sh)) * WL + w0 + c4;
      gld16(src, &lds0[g * 256]);
    }
    if (wv == 3) {  // wave 3's 5th instr: stage disp (lanes 32-63 dup)
      const float* dsrc = disp + ((size_t)b * NH + (h0 + ((lane >> 4) & 1))) * WL +
                          w0 + (lane & 15);
      gld4(dsrc, &lds0[DISPOFF]);
    }
  }

  asm volatile("s_waitcnt vmcnt(0)" ::: "memory");
  __syncthreads();

  // ---- sample: wave wv = level ----
  switch (wv) {
    case 0: sample_level<0>(lds0, lane, b, h0, w0, out); break;
    case 1: sample_level<1>(lds0, lane, b, h0, w0, out); break;
    case 2: sample_level<2>(lds0, lane, b, h0, w0, out); break;
    default: sample_level<3>(lds0, lane, b, h0, w0, out); break;
  }
}

extern "C" void kernel_launch(void* const* d_in, const int* in_sizes, int n_in,
                              void* d_out, int out_size, void* d_ws,
                              size_t ws_size, hipStream_t stream) {
  const float* corr = (const float*)d_in[0];
  const float* disp = (const float*)d_in[1];
  float* out = (float*)d_out;
  corr_sample_kernel<<<NBLK, 256, 0, stream>>>(corr, disp, out);
}